// Round 6
// baseline (586.705 us; speedup 1.0000x reference)
//
#include <hip/hip_runtime.h>

#define T_SEQ 2048
#define NH    6
#define HD    128
#define CDIM  768
#define NQKV  2304
#define MROWS 8192   // B*T = 4*2048

typedef __attribute__((ext_vector_type(8))) short bf16x8;
typedef __attribute__((ext_vector_type(4))) float f32x4;

__device__ __forceinline__ unsigned short f2bf(float f){
  unsigned int u = __builtin_bit_cast(unsigned int, f);
  u += 0x7fffu + ((u >> 16) & 1u);          // round-to-nearest-even
  return (unsigned short)(u >> 16);
}
__device__ __forceinline__ float bf2f(unsigned short h){
  unsigned int u = ((unsigned int)h) << 16;
  return __builtin_bit_cast(float, u);
}

// async global->LDS, 16B per lane; LDS dest is wave-uniform base + lane*16
__device__ __forceinline__ void gload_lds16(const void* g, void* l){
  __builtin_amdgcn_global_load_lds(
      (const __attribute__((address_space(1))) unsigned int*)g,
      (__attribute__((address_space(3))) unsigned int*)l, 16, 0, 0);
}

// ---------------- f32 -> bf16 conversion (vectorized) ----------------
__global__ __launch_bounds__(256) void cvt_f32_bf16(
    const float* __restrict__ in, unsigned short* __restrict__ out, int n4){
  int i = blockIdx.x * 256 + threadIdx.x;
  if (i >= n4) return;
  float4 v = reinterpret_cast<const float4*>(in)[i];
  ushort4 o;
  o.x = f2bf(v.x); o.y = f2bf(v.y); o.z = f2bf(v.z); o.w = f2bf(v.w);
  reinterpret_cast<ushort4*>(out)[i] = o;
}

// 4 weight matrices (each CDIM*CDIM f32) -> contiguous bf16 (Wqkv then Wo)
__global__ __launch_bounds__(256) void cvt_w4(
    const float* __restrict__ w0, const float* __restrict__ w1,
    const float* __restrict__ w2, const float* __restrict__ w3,
    unsigned short* __restrict__ out){
  const int which = blockIdx.y;
  const float* src = which == 0 ? w0 : which == 1 ? w1 : which == 2 ? w2 : w3;
  int i = blockIdx.x * 256 + threadIdx.x;           // in float4 units
  float4 v = reinterpret_cast<const float4*>(src)[i];
  ushort4 o;
  o.x = f2bf(v.x); o.y = f2bf(v.y); o.z = f2bf(v.z); o.w = f2bf(v.w);
  reinterpret_cast<ushort4*>(out + (size_t)which * CDIM * CDIM)[i] = o;
}

// ---------------- GEMM: C = A(MxK,bf16) * B(NxK,bf16)^T ----------------
// m97 structure: 128x128 tile, BK=64, global_load_lds(16B) into linear LDS,
// XOR slot-swizzle (slot ^= row&7) applied on global-source AND ds_read side.
template<int BF16OUT>
__global__ __launch_bounds__(256) void gemm_bt(
    const unsigned short* __restrict__ A,
    const unsigned short* __restrict__ B,
    void* __restrict__ Cv, int M, int N, int K)
{
  __shared__ unsigned short As[128 * 64];   // linear, row = 64 elems = 128B
  __shared__ unsigned short Bs[128 * 64];
  const int tid  = threadIdx.x;
  const int lane = tid & 63;
  const int wave = tid >> 6;
  const int wm = wave >> 1, wn = wave & 1;
  const int lr = lane & 15, lg = lane >> 4;
  const int srow = lane >> 3;               // staging row within 8-row seg
  const int sslot = (lane & 7) ^ (lane >> 3);  // pre-swizzled global slot
  const int row0 = blockIdx.x * 128, col0 = blockIdx.y * 128;

  f32x4 acc[4][4];
  const f32x4 z = {0.f, 0.f, 0.f, 0.f};
  #pragma unroll
  for (int i = 0; i < 4; ++i)
    #pragma unroll
    for (int j = 0; j < 4; ++j) acc[i][j] = z;

  for (int k0 = 0; k0 < K; k0 += 64){
    #pragma unroll
    for (int i = 0; i < 4; ++i){
      int seg = wave * 4 + i;                 // 8 rows per 1KB segment
      int r = seg * 8 + srow;
      gload_lds16(&A[(size_t)(row0 + r) * K + k0 + sslot * 8], &As[seg * 512]);
      gload_lds16(&B[(size_t)(col0 + r) * K + k0 + sslot * 8], &Bs[seg * 512]);
    }
    __syncthreads();
    #pragma unroll
    for (int kk = 0; kk < 64; kk += 32){
      bf16x8 af[4], bfr[4];
      #pragma unroll
      for (int mi = 0; mi < 4; ++mi)
        af[mi] = *reinterpret_cast<const bf16x8*>(
            &As[(wm*64 + mi*16 + lr) * 64 + ((((kk>>3) + lg) ^ (lr & 7)) * 8)]);
      #pragma unroll
      for (int ni = 0; ni < 4; ++ni)
        bfr[ni] = *reinterpret_cast<const bf16x8*>(
            &Bs[(wn*64 + ni*16 + lr) * 64 + ((((kk>>3) + lg) ^ (lr & 7)) * 8)]);
      #pragma unroll
      for (int mi = 0; mi < 4; ++mi)
        #pragma unroll
        for (int ni = 0; ni < 4; ++ni)
          acc[mi][ni] = __builtin_amdgcn_mfma_f32_16x16x32_bf16(af[mi], bfr[ni], acc[mi][ni], 0, 0, 0);
    }
    __syncthreads();
  }
  #pragma unroll
  for (int mi = 0; mi < 4; ++mi){
    #pragma unroll
    for (int ni = 0; ni < 4; ++ni){
      #pragma unroll
      for (int r = 0; r < 4; ++r){
        int row = row0 + wm*64 + mi*16 + lg*4 + r;   // C/D: row=(l>>4)*4+reg
        int col = col0 + wn*64 + ni*16 + lr;         //       col=l&15
        if (BF16OUT)
          reinterpret_cast<unsigned short*>(Cv)[(size_t)row * N + col] = f2bf(acc[mi][ni][r]);
        else
          reinterpret_cast<float*>(Cv)[(size_t)row * N + col] = acc[mi][ni][r];
      }
    }
  }
}

// ---------------- RoPE + RMSNorm for Q,K; writes (B,H,T,D) bf16 ----------------
__global__ __launch_bounds__(256) void rope_rms(
    const unsigned short* __restrict__ QKVb,
    const float* __restrict__ cosp, const float* __restrict__ sinp,
    unsigned short* __restrict__ Qb, unsigned short* __restrict__ Kb)
{
  const int bt    = blockIdx.x;            // b*T + t
  const int task  = blockIdx.y * 4 + (threadIdx.x >> 6);   // 0..11
  const int which = task / NH;             // 0=q, 1=k
  const int h     = task % NH;
  const int t     = bt & (T_SEQ - 1);
  const int b     = bt >> 11;
  const int lane  = threadIdx.x & 63;      // 0..63
  const unsigned short* src = QKVb + (size_t)bt * NQKV + which * CDIM + h * HD;
  float x1 = bf2f(src[lane]);
  float x2 = bf2f(src[lane + 64]);
  float c = cosp[t * 64 + lane];
  float s = sinp[t * 64 + lane];
  float y1 = x1 * c + x2 * s;
  float y2 = x2 * c - x1 * s;
  float ss = y1 * y1 + y2 * y2;
  #pragma unroll
  for (int off = 1; off < 64; off <<= 1) ss += __shfl_xor(ss, off);
  float inv = rsqrtf(ss * (1.0f / 128.0f) + 1e-15f);
  unsigned short* dst = (which ? Kb : Qb) + ((size_t)(b * NH + h) * T_SEQ + t) * HD;
  dst[lane]      = f2bf(y1 * inv);
  dst[lane + 64] = f2bf(y2 * inv);
}

// ---------------- V transpose: QKV v-slice (B,T,H,D) -> Vt (B*H, D, T) ----------------
__global__ __launch_bounds__(256) void transpose_v(
    const unsigned short* __restrict__ QKVb, unsigned short* __restrict__ Vt)
{
  __shared__ unsigned short tile[64][66];
  const int tid = threadIdx.x;
  const int t0  = blockIdx.x * 64;          // 32 tiles along T
  const int hd  = blockIdx.y;               // 0..11 : (head, d-half)
  const int b   = blockIdx.z;               // 0..3
  const int h = hd >> 1, dhalf = (hd & 1) * 64;
  const unsigned short* src = QKVb + (size_t)b * T_SEQ * NQKV + 2 * CDIM + h * HD + dhalf;
  #pragma unroll
  for (int it = 0; it < 2; ++it){
    int ch = tid + it * 256;                // 64 rows x 8 chunks
    int r = ch >> 3, cc = (ch & 7) * 8;
    *reinterpret_cast<int4*>(&tile[r][cc]) =
        *reinterpret_cast<const int4*>(&src[(size_t)(t0 + r) * NQKV + cc]);
  }
  __syncthreads();
  unsigned short* dst = Vt + ((size_t)(b * NH + h) * HD + dhalf) * T_SEQ + t0;
  #pragma unroll
  for (int it = 0; it < 2; ++it){
    int ch = tid + it * 256;                // 64 d-rows x 8 chunks
    int d = ch >> 3, cc = (ch & 7) * 8;
    union { int4 v; unsigned short u[8]; } w;
    #pragma unroll
    for (int j = 0; j < 8; ++j) w.u[j] = tile[cc + j][d];
    *reinterpret_cast<int4*>(&dst[(size_t)d * T_SEQ + cc]) = w.v;
  }
}

// ---------------- causal flash attention (no staging, no barriers) ----------------
// 4 independent waves/block, 16 q-rows each. K and V fragments are read
// DIRECTLY from global (L1/L2-served; K/V per head = 1MB, hot). The only
// LDS is a per-wave 4KB P-relayout buffer (same-wave write->read, no sync).
__global__ __launch_bounds__(256) void attn_fwd(
    const unsigned short* __restrict__ Qb,
    const unsigned short* __restrict__ Kb,
    const unsigned short* __restrict__ Vt,     // (B*H, D, T)
    unsigned short* __restrict__ AO)
{
  __shared__ float Ps_all[4][16 * 64];        // 4KB per wave
  const int tid = threadIdx.x;
  const int lane = tid & 63, wave = tid >> 6;
  const int lr = lane & 15, lg = lane >> 4;
  float* Ps = Ps_all[wave];
  const int bh = blockIdx.y;
  const int b = bh / NH, h = bh % NH;
  const int q0 = (gridDim.x - 1 - blockIdx.x) * 64;   // big causal blocks first
  const int qw = q0 + wave * 16;
  const int ntile = ((qw + 15) >> 6) + 1;             // per-wave tile count
  const unsigned short* Qp = Qb + (size_t)bh * T_SEQ * HD;
  const unsigned short* Kp = Kb + (size_t)bh * T_SEQ * HD;
  const unsigned short* Vp = Vt + (size_t)bh * HD * T_SEQ;

  // Q fragments in registers: A[m=l&15][k=8*(l>>4)+j], 4 k-chunks of 32
  bf16x8 qf[4];
  #pragma unroll
  for (int c4 = 0; c4 < 4; ++c4)
    qf[c4] = *reinterpret_cast<const bf16x8*>(&Qp[(size_t)(qw + lr) * HD + c4 * 32 + lg * 8]);

  const f32x4 z = {0.f, 0.f, 0.f, 0.f};
  f32x4 o[8];
  #pragma unroll
  for (int dt = 0; dt < 8; ++dt) o[dt] = z;
  float mrun[4], lrun[4];
  #pragma unroll
  for (int r = 0; r < 4; ++r){ mrun[r] = -__builtin_inff(); lrun[r] = 0.f; }
  const float scl = 0.08838834764831845f;   // 1/sqrt(128)

  for (int t = 0; t < ntile; ++t){
    const int kv0 = t * 64;

    // ---- S = Q K^T (16 x 64): K fragments straight from global ----
    f32x4 s[4];
    #pragma unroll
    for (int nt = 0; nt < 4; ++nt) s[nt] = z;
    __builtin_amdgcn_s_setprio(1);
    #pragma unroll
    for (int c4 = 0; c4 < 4; ++c4){
      #pragma unroll
      for (int nt = 0; nt < 4; ++nt){
        bf16x8 kf = *reinterpret_cast<const bf16x8*>(
            &Kp[(size_t)(kv0 + nt * 16 + lr) * HD + c4 * 32 + lg * 8]);
        s[nt] = __builtin_amdgcn_mfma_f32_16x16x32_bf16(qf[c4], kf, s[nt], 0, 0, 0);
      }
    }
    __builtin_amdgcn_s_setprio(0);

    // ---- scale + causal mask ----
    if (kv0 + 63 > qw){
      #pragma unroll
      for (int nt = 0; nt < 4; ++nt){
        int kg = kv0 + nt * 16 + lr;
        #pragma unroll
        for (int r = 0; r < 4; ++r){
          int qg = qw + lg * 4 + r;
          s[nt][r] = (kg <= qg) ? s[nt][r] * scl : -__builtin_inff();
        }
      }
    } else {
      #pragma unroll
      for (int nt = 0; nt < 4; ++nt)
        #pragma unroll
        for (int r = 0; r < 4; ++r) s[nt][r] *= scl;
    }

    // ---- online softmax (per row; 16-lane shuffle reductions) ----
    float pm[4], rs[4];
    #pragma unroll
    for (int r = 0; r < 4; ++r)
      pm[r] = fmaxf(fmaxf(s[0][r], s[1][r]), fmaxf(s[2][r], s[3][r]));
    #pragma unroll
    for (int off = 1; off < 16; off <<= 1){
      #pragma unroll
      for (int r = 0; r < 4; ++r) pm[r] = fmaxf(pm[r], __shfl_xor(pm[r], off));
    }
    // exact defer-rescale: only rescale when the running max grew (wave-uniform)
    bool grow = false;
    #pragma unroll
    for (int r = 0; r < 4; ++r) grow = grow || (pm[r] > mrun[r]);
    if (__any(grow)){
      float sc[4];
      #pragma unroll
      for (int r = 0; r < 4; ++r){
        float mn = fmaxf(mrun[r], pm[r]);
        sc[r] = (mrun[r] == -__builtin_inff()) ? 0.f : __expf(mrun[r] - mn);
        mrun[r] = mn;
      }
      #pragma unroll
      for (int r = 0; r < 4; ++r) lrun[r] *= sc[r];
      #pragma unroll
      for (int dt = 0; dt < 8; ++dt)
        #pragma unroll
        for (int r = 0; r < 4; ++r) o[dt][r] *= sc[r];
    }
    #pragma unroll
    for (int r = 0; r < 4; ++r) rs[r] = 0.f;
    #pragma unroll
    for (int nt = 0; nt < 4; ++nt)
      #pragma unroll
      for (int r = 0; r < 4; ++r){
        float p = __expf(s[nt][r] - mrun[r]);
        s[nt][r] = p;
        rs[r] += p;
      }
    #pragma unroll
    for (int off = 1; off < 16; off <<= 1){
      #pragma unroll
      for (int r = 0; r < 4; ++r) rs[r] += __shfl_xor(rs[r], off);
    }
    #pragma unroll
    for (int r = 0; r < 4; ++r) lrun[r] += rs[r];

    // ---- P relayout via per-wave LDS (same-wave; XOR-swizzled cols) ----
    #pragma unroll
    for (int nt = 0; nt < 4; ++nt)
      #pragma unroll
      for (int r = 0; r < 4; ++r){
        int row = lg * 4 + r;
        Ps[row * 64 + ((nt * 16 + lr) ^ ((row & 7) << 2))] = s[nt][r];
      }

    // ---- O += P V: V fragments straight from global Vt ----
    __builtin_amdgcn_s_setprio(1);
    #pragma unroll
    for (int kc = 0; kc < 2; ++kc){
      float4 p0 = *reinterpret_cast<const float4*>(
          &Ps[lr * 64 + ((kc * 32 + lg * 8) ^ ((lr & 7) << 2))]);
      float4 p1 = *reinterpret_cast<const float4*>(
          &Ps[lr * 64 + (((kc * 32 + lg * 8) + 4) ^ ((lr & 7) << 2))]);
      union { bf16x8 v; unsigned short u[8]; } pa;
      pa.u[0] = f2bf(p0.x); pa.u[1] = f2bf(p0.y); pa.u[2] = f2bf(p0.z); pa.u[3] = f2bf(p0.w);
      pa.u[4] = f2bf(p1.x); pa.u[5] = f2bf(p1.y); pa.u[6] = f2bf(p1.z); pa.u[7] = f2bf(p1.w);
      #pragma unroll
      for (int dt = 0; dt < 8; ++dt){
        bf16x8 vf = *reinterpret_cast<const bf16x8*>(
            &Vp[(size_t)(dt * 16 + lr) * T_SEQ + kv0 + kc * 32 + lg * 8]);
        o[dt] = __builtin_amdgcn_mfma_f32_16x16x32_bf16(pa.v, vf, o[dt], 0, 0, 0);
      }
    }
    __builtin_amdgcn_s_setprio(0);
  }

  // ---- epilogue: O /= l; write AO in (B,T,C) bf16 ----
  float inv[4];
  #pragma unroll
  for (int r = 0; r < 4; ++r) inv[r] = 1.0f / lrun[r];
  #pragma unroll
  for (int dt = 0; dt < 8; ++dt)
    #pragma unroll
    for (int r = 0; r < 4; ++r)
      AO[((size_t)b * T_SEQ + qw + lg * 4 + r) * CDIM + h * HD + dt * 16 + lr] =
          f2bf(o[dt][r] * inv[r]);
}

// ---------------- launch ----------------
extern "C" void kernel_launch(void* const* d_in, const int* in_sizes, int n_in,
                              void* d_out, int out_size, void* d_ws, size_t ws_size,
                              hipStream_t stream)
{
  (void)in_sizes; (void)n_in; (void)out_size; (void)ws_size;
  const float* x    = (const float*)d_in[0];
  const float* cosp = (const float*)d_in[1];
  const float* sinp = (const float*)d_in[2];
  const float* Wq   = (const float*)d_in[3];
  const float* Wk   = (const float*)d_in[4];
  const float* Wv   = (const float*)d_in[5];
  const float* Wo   = (const float*)d_in[6];
  float* out = (float*)d_out;

  // workspace layout (all bf16), ~105 MB total
  unsigned short* xb    = (unsigned short*)d_ws;
  unsigned short* Wqkvb = xb    + (size_t)MROWS * CDIM;
  unsigned short* Wob   = Wqkvb + (size_t)NQKV * CDIM;
  unsigned short* QKVb  = Wob   + (size_t)CDIM * CDIM;
  unsigned short* Qb    = QKVb  + (size_t)MROWS * NQKV;
  unsigned short* Kb    = Qb    + (size_t)MROWS * CDIM;
  unsigned short* Vtb   = Kb    + (size_t)MROWS * CDIM;
  unsigned short* AO    = Vtb   + (size_t)MROWS * CDIM;

  int n4x = MROWS * CDIM / 4;
  cvt_f32_bf16<<<(n4x + 255) / 256, 256, 0, stream>>>(x, xb, n4x);
  // 4 weight cvts in one launch (Wqkvb and Wob are contiguous in ws)
  cvt_w4<<<dim3(CDIM * CDIM / 4 / 256, 4), 256, 0, stream>>>(Wq, Wk, Wv, Wo, Wqkvb);

  // fused QKV projection: (8192x768) @ (2304x768)^T -> bf16 QKV
  gemm_bt<1><<<dim3(MROWS / 128, NQKV / 128), 256, 0, stream>>>(xb, Wqkvb, QKVb, MROWS, NQKV, CDIM);
  // RoPE + RMSNorm -> Q,K in (B,H,T,D)
  rope_rms<<<dim3(MROWS, 3), 256, 0, stream>>>(QKVb, cosp, sinp, Qb, Kb);
  // V transpose -> Vt (B*H, D, T)
  transpose_v<<<dim3(T_SEQ / 64, 12, 4), 256, 0, stream>>>(QKVb, Vtb);
  // causal flash attention -> AO in (B,T,C)
  attn_fwd<<<dim3(T_SEQ / 64, 4 * NH), 256, 0, stream>>>(Qb, Kb, Vtb, AO);
  // output projection -> f32 d_out
  gemm_bt<0><<<dim3(MROWS / 128, CDIM / 128), 256, 0, stream>>>(AO, Wob, out, MROWS, CDIM, CDIM);
}

// Round 7
// 217.670 us; speedup vs baseline: 2.6954x; 2.6954x over previous
//
#include <hip/hip_runtime.h>

#define T_SEQ 2048
#define NH    6
#define HD    128
#define CDIM  768
#define NQKV  2304
#define MROWS 8192   // B*T = 4*2048
#define NSLOT 1920   // 80 chunks per (b,h) * 24

typedef __attribute__((ext_vector_type(8))) short bf16x8;
typedef __attribute__((ext_vector_type(4))) float f32x4;

__device__ __forceinline__ unsigned short f2bf(float f){
  unsigned int u = __builtin_bit_cast(unsigned int, f);
  u += 0x7fffu + ((u >> 16) & 1u);          // round-to-nearest-even
  return (unsigned short)(u >> 16);
}
__device__ __forceinline__ float bf2f(unsigned short h){
  unsigned int u = ((unsigned int)h) << 16;
  return __builtin_bit_cast(float, u);
}

// async global->LDS, 16B per lane; LDS dest is wave-uniform base + lane*16
__device__ __forceinline__ void gload_lds16(const void* g, void* l){
  __builtin_amdgcn_global_load_lds(
      (const __attribute__((address_space(1))) unsigned int*)g,
      (__attribute__((address_space(3))) unsigned int*)l, 16, 0, 0);
}

// chunks before q-block q (CHUNK=8 tiles)
__device__ __forceinline__ int offq(int q){
  return q < 8 ? q : q < 16 ? 8 + 2*(q-8) : q < 24 ? 24 + 3*(q-16) : 48 + 4*(q-24);
}

// ---------------- f32 -> bf16 conversion (vectorized) ----------------
__global__ __launch_bounds__(256) void cvt_f32_bf16(
    const float* __restrict__ in, unsigned short* __restrict__ out, int n4){
  int i = blockIdx.x * 256 + threadIdx.x;
  if (i >= n4) return;
  float4 v = reinterpret_cast<const float4*>(in)[i];
  ushort4 o;
  o.x = f2bf(v.x); o.y = f2bf(v.y); o.z = f2bf(v.z); o.w = f2bf(v.w);
  reinterpret_cast<ushort4*>(out)[i] = o;
}

// 4 weight matrices (each CDIM*CDIM f32) -> contiguous bf16 (Wqkv then Wo)
__global__ __launch_bounds__(256) void cvt_w4(
    const float* __restrict__ w0, const float* __restrict__ w1,
    const float* __restrict__ w2, const float* __restrict__ w3,
    unsigned short* __restrict__ out){
  const int which = blockIdx.y;
  const float* src = which == 0 ? w0 : which == 1 ? w1 : which == 2 ? w2 : w3;
  int i = blockIdx.x * 256 + threadIdx.x;           // in float4 units
  float4 v = reinterpret_cast<const float4*>(src)[i];
  ushort4 o;
  o.x = f2bf(v.x); o.y = f2bf(v.y); o.z = f2bf(v.z); o.w = f2bf(v.w);
  reinterpret_cast<ushort4*>(out + (size_t)which * CDIM * CDIM)[i] = o;
}

// ---------------- GEMM: C = A(MxK,bf16) * B(NxK,bf16)^T ----------------
// 128x128 tile, BK=64, global_load_lds(16B) into linear LDS,
// XOR slot-swizzle (slot ^= row&7) applied on global-source AND ds_read side.
template<int BF16OUT>
__global__ __launch_bounds__(256) void gemm_bt(
    const unsigned short* __restrict__ A,
    const unsigned short* __restrict__ B,
    void* __restrict__ Cv, int M, int N, int K)
{
  __shared__ unsigned short As[128 * 64];   // linear, row = 64 elems = 128B
  __shared__ unsigned short Bs[128 * 64];
  const int tid  = threadIdx.x;
  const int lane = tid & 63;
  const int wave = tid >> 6;
  const int wm = wave >> 1, wn = wave & 1;
  const int lr = lane & 15, lg = lane >> 4;
  const int srow = lane >> 3;               // staging row within 8-row seg
  const int sslot = (lane & 7) ^ (lane >> 3);  // pre-swizzled global slot
  const int row0 = blockIdx.x * 128, col0 = blockIdx.y * 128;

  f32x4 acc[4][4];
  const f32x4 z = {0.f, 0.f, 0.f, 0.f};
  #pragma unroll
  for (int i = 0; i < 4; ++i)
    #pragma unroll
    for (int j = 0; j < 4; ++j) acc[i][j] = z;

  for (int k0 = 0; k0 < K; k0 += 64){
    #pragma unroll
    for (int i = 0; i < 4; ++i){
      int seg = wave * 4 + i;                 // 8 rows per 1KB segment
      int r = seg * 8 + srow;
      gload_lds16(&A[(size_t)(row0 + r) * K + k0 + sslot * 8], &As[seg * 512]);
      gload_lds16(&B[(size_t)(col0 + r) * K + k0 + sslot * 8], &Bs[seg * 512]);
    }
    __syncthreads();
    #pragma unroll
    for (int kk = 0; kk < 64; kk += 32){
      bf16x8 af[4], bfr[4];
      #pragma unroll
      for (int mi = 0; mi < 4; ++mi)
        af[mi] = *reinterpret_cast<const bf16x8*>(
            &As[(wm*64 + mi*16 + lr) * 64 + ((((kk>>3) + lg) ^ (lr & 7)) * 8)]);
      #pragma unroll
      for (int ni = 0; ni < 4; ++ni)
        bfr[ni] = *reinterpret_cast<const bf16x8*>(
            &Bs[(wn*64 + ni*16 + lr) * 64 + ((((kk>>3) + lg) ^ (lr & 7)) * 8)]);
      #pragma unroll
      for (int mi = 0; mi < 4; ++mi)
        #pragma unroll
        for (int ni = 0; ni < 4; ++ni)
          acc[mi][ni] = __builtin_amdgcn_mfma_f32_16x16x32_bf16(af[mi], bfr[ni], acc[mi][ni], 0, 0, 0);
    }
    __syncthreads();
  }
  #pragma unroll
  for (int mi = 0; mi < 4; ++mi){
    #pragma unroll
    for (int ni = 0; ni < 4; ++ni){
      #pragma unroll
      for (int r = 0; r < 4; ++r){
        int row = row0 + wm*64 + mi*16 + lg*4 + r;   // C/D: row=(l>>4)*4+reg
        int col = col0 + wn*64 + ni*16 + lr;         //       col=l&15
        if (BF16OUT)
          reinterpret_cast<unsigned short*>(Cv)[(size_t)row * N + col] = f2bf(acc[mi][ni][r]);
        else
          reinterpret_cast<float*>(Cv)[(size_t)row * N + col] = acc[mi][ni][r];
      }
    }
  }
}

// ---------------- RoPE + RMSNorm for Q,K; IN PLACE in QKV ----------------
__global__ __launch_bounds__(256) void rope_rms(
    unsigned short* __restrict__ QKVb,
    const float* __restrict__ cosp, const float* __restrict__ sinp)
{
  const int bt    = blockIdx.x;            // b*T + t
  const int task  = blockIdx.y * 4 + (threadIdx.x >> 6);   // 0..11
  const int which = task / NH;             // 0=q, 1=k
  const int h     = task % NH;
  const int t     = bt & (T_SEQ - 1);
  const int lane  = threadIdx.x & 63;      // 0..63
  unsigned short* p = QKVb + (size_t)bt * NQKV + which * CDIM + h * HD;
  float x1 = bf2f(p[lane]);
  float x2 = bf2f(p[lane + 64]);
  float c = cosp[t * 64 + lane];
  float s = sinp[t * 64 + lane];
  float y1 = x1 * c + x2 * s;
  float y2 = x2 * c - x1 * s;
  float ss = y1 * y1 + y2 * y2;
  #pragma unroll
  for (int off = 1; off < 64; off <<= 1) ss += __shfl_xor(ss, off);
  float inv = rsqrtf(ss * (1.0f / 128.0f) + 1e-15f);
  p[lane]      = f2bf(y1 * inv);
  p[lane + 64] = f2bf(y2 * inv);
}

// ---------------- V transpose: QKV v-slice (B,T,H,D) -> Vt (B*H, D, T) ----------------
__global__ __launch_bounds__(256) void transpose_v(
    const unsigned short* __restrict__ QKVb, unsigned short* __restrict__ Vt)
{
  __shared__ unsigned short tile[64][66];
  const int tid = threadIdx.x;
  const int t0  = blockIdx.x * 64;          // 32 tiles along T
  const int hd  = blockIdx.y;               // 0..11 : (head, d-half)
  const int b   = blockIdx.z;               // 0..3
  const int h = hd >> 1, dhalf = (hd & 1) * 64;
  const unsigned short* src = QKVb + (size_t)b * T_SEQ * NQKV + 2 * CDIM + h * HD + dhalf;
  #pragma unroll
  for (int it = 0; it < 2; ++it){
    int ch = tid + it * 256;                // 64 rows x 8 chunks
    int r = ch >> 3, cc = (ch & 7) * 8;
    *reinterpret_cast<int4*>(&tile[r][cc]) =
        *reinterpret_cast<const int4*>(&src[(size_t)(t0 + r) * NQKV + cc]);
  }
  __syncthreads();
  unsigned short* dst = Vt + ((size_t)(b * NH + h) * HD + dhalf) * T_SEQ + t0;
  #pragma unroll
  for (int it = 0; it < 2; ++it){
    int ch = tid + it * 256;                // 64 d-rows x 8 chunks
    int d = ch >> 3, cc = (ch & 7) * 8;
    union { int4 v; unsigned short u[8]; } w;
    #pragma unroll
    for (int j = 0; j < 8; ++j) w.u[j] = tile[cc + j][d];
    *reinterpret_cast<int4*>(&dst[(size_t)d * T_SEQ + cc]) = w.v;
  }
}

// ---------------- causal flash attention, SPLIT-KV ----------------
// Each block: one q-block (64 rows) x one KV chunk (<=8 tiles of 64).
// 4 waves, 16 q-rows/wave. Round-2 proven staging (padded int4 LDS),
// Ps aliased onto Ks (dead after QK^T). nc==1 -> final AO; else partial.
__global__ __launch_bounds__(256) void attn_fwd(
    const unsigned short* __restrict__ QKVb,   // rope'd Q,K + V in place
    const unsigned short* __restrict__ Vt,     // (B*H, D, T)
    unsigned short* __restrict__ AO,
    float* __restrict__ Op, float* __restrict__ Mp, float* __restrict__ Lp,
    int split)
{
  __shared__ unsigned short Ks[64][136];    // 17408B; Ps aliases this
  __shared__ unsigned short Vs[128][72];    // 18432B
  const int tid = threadIdx.x;
  const int lane = tid & 63, wave = tid >> 6;
  const int lr = lane & 15, lg = lane >> 4;
  float* Ps = reinterpret_cast<float*>(&Ks[0][0]) + wave * 1024;  // 16x64 f32

  const int bh = blockIdx.y;
  const int b = bh / NH, h = bh % NH;
  int q, c, nc;
  if (split){
    int L = blockIdx.x;
    if (L < 8)      { q = L; c = 0; }
    else if (L < 24){ int m = L - 8;  q = 8 + (m >> 1); c = m & 1; }
    else if (L < 48){ int m = L - 24; q = 16 + m / 3;   c = m % 3; }
    else            { int m = L - 48; q = 24 + (m >> 2); c = m & 3; }
    nc = (q + 8) >> 3;                 // ceil((q+1)/8)
  } else { q = blockIdx.x; c = 0; nc = 1; }
  const int q0 = q * 64;
  const int qw = q0 + wave * 16;
  const int tbeg = c * 8;
  const int tend = split ? ((tbeg + 8 < q + 1) ? tbeg + 8 : q + 1) : q + 1;

  const unsigned short* Qp = QKVb + (size_t)(b * T_SEQ) * NQKV + h * HD;
  const unsigned short* Kp = QKVb + (size_t)(b * T_SEQ) * NQKV + CDIM + h * HD;
  const unsigned short* Vp = Vt + (size_t)bh * HD * T_SEQ;

  // Q fragments in registers: A[m=l&15][k=8*(l>>4)+j], 4 k-chunks of 32
  bf16x8 qf[4];
  #pragma unroll
  for (int c4 = 0; c4 < 4; ++c4)
    qf[c4] = *reinterpret_cast<const bf16x8*>(&Qp[(size_t)(qw + lr) * NQKV + c4 * 32 + lg * 8]);

  const f32x4 z = {0.f, 0.f, 0.f, 0.f};
  f32x4 o[8];
  #pragma unroll
  for (int dt = 0; dt < 8; ++dt) o[dt] = z;
  float mrun[4], lrun[4];
  #pragma unroll
  for (int r = 0; r < 4; ++r){ mrun[r] = -__builtin_inff(); lrun[r] = 0.f; }
  const float scl = 0.08838834764831845f;   // 1/sqrt(128)

  for (int t = tbeg; t < tend; ++t){
    const int kv0 = t * 64;
    // ---- stage K rows (from QKV) and V^T rows (both coalesced) ----
    #pragma unroll
    for (int it = 0; it < 4; ++it){
      int ch = tid + it * 256;               // K: 64 rows x 16 chunks
      int r = ch >> 4, cc = (ch & 15) * 8;
      *reinterpret_cast<int4*>(&Ks[r][cc]) =
          *reinterpret_cast<const int4*>(&Kp[(size_t)(kv0 + r) * NQKV + cc]);
      int rv = ch >> 3, cv = (ch & 7) * 8;   // V: 128 d-rows x 8 chunks
      *reinterpret_cast<int4*>(&Vs[rv][cv]) =
          *reinterpret_cast<const int4*>(&Vp[(size_t)rv * T_SEQ + kv0 + cv]);
    }
    __syncthreads();

    // ---- S = Q K^T (16 x 64) ----
    f32x4 s[4];
    #pragma unroll
    for (int nt = 0; nt < 4; ++nt) s[nt] = z;
    __builtin_amdgcn_s_setprio(1);
    #pragma unroll
    for (int c4 = 0; c4 < 4; ++c4){
      #pragma unroll
      for (int nt = 0; nt < 4; ++nt){
        bf16x8 kf = *reinterpret_cast<const bf16x8*>(&Ks[nt * 16 + lr][c4 * 32 + lg * 8]);
        s[nt] = __builtin_amdgcn_mfma_f32_16x16x32_bf16(qf[c4], kf, s[nt], 0, 0, 0);
      }
    }
    __builtin_amdgcn_s_setprio(0);
    __syncthreads();   // Ks dead; Ps may overwrite

    // ---- scale + causal mask (only the diagonal tile masks) ----
    if (kv0 + 63 > qw){
      #pragma unroll
      for (int nt = 0; nt < 4; ++nt){
        int kg = kv0 + nt * 16 + lr;
        #pragma unroll
        for (int r = 0; r < 4; ++r){
          int qg = qw + lg * 4 + r;
          s[nt][r] = (kg <= qg) ? s[nt][r] * scl : -__builtin_inff();
        }
      }
    } else {
      #pragma unroll
      for (int nt = 0; nt < 4; ++nt)
        #pragma unroll
        for (int r = 0; r < 4; ++r) s[nt][r] *= scl;
    }

    // ---- online softmax (per row; 16-lane shuffle reductions) ----
    float pm[4], rs[4];
    #pragma unroll
    for (int r = 0; r < 4; ++r)
      pm[r] = fmaxf(fmaxf(s[0][r], s[1][r]), fmaxf(s[2][r], s[3][r]));
    #pragma unroll
    for (int off = 1; off < 16; off <<= 1){
      #pragma unroll
      for (int r = 0; r < 4; ++r) pm[r] = fmaxf(pm[r], __shfl_xor(pm[r], off));
    }
    bool grow = false;
    #pragma unroll
    for (int r = 0; r < 4; ++r) grow = grow || (pm[r] > mrun[r]);
    if (__any(grow)){
      float sc[4];
      #pragma unroll
      for (int r = 0; r < 4; ++r){
        float mn = fmaxf(mrun[r], pm[r]);
        sc[r] = (mrun[r] == -__builtin_inff()) ? 0.f : __expf(mrun[r] - mn);
        mrun[r] = mn;
      }
      #pragma unroll
      for (int r = 0; r < 4; ++r) lrun[r] *= sc[r];
      #pragma unroll
      for (int dt = 0; dt < 8; ++dt)
        #pragma unroll
        for (int r = 0; r < 4; ++r) o[dt][r] *= sc[r];
    }
    #pragma unroll
    for (int r = 0; r < 4; ++r) rs[r] = 0.f;
    #pragma unroll
    for (int nt = 0; nt < 4; ++nt)
      #pragma unroll
      for (int r = 0; r < 4; ++r){
        float p = __expf(s[nt][r] - mrun[r]);
        s[nt][r] = p;
        rs[r] += p;
      }
    #pragma unroll
    for (int off = 1; off < 16; off <<= 1){
      #pragma unroll
      for (int r = 0; r < 4; ++r) rs[r] += __shfl_xor(rs[r], off);
    }
    #pragma unroll
    for (int r = 0; r < 4; ++r) lrun[r] += rs[r];

    // ---- P relayout via per-wave LDS (aliased on Ks; XOR-swizzled) ----
    #pragma unroll
    for (int nt = 0; nt < 4; ++nt)
      #pragma unroll
      for (int r = 0; r < 4; ++r){
        int row = lg * 4 + r;
        Ps[row * 64 + ((nt * 16 + lr) ^ ((row & 7) << 2))] = s[nt][r];
      }

    // ---- O += P V ----
    __builtin_amdgcn_s_setprio(1);
    #pragma unroll
    for (int kc = 0; kc < 2; ++kc){
      float4 p0 = *reinterpret_cast<const float4*>(
          &Ps[lr * 64 + ((kc * 32 + lg * 8) ^ ((lr & 7) << 2))]);
      float4 p1 = *reinterpret_cast<const float4*>(
          &Ps[lr * 64 + (((kc * 32 + lg * 8) + 4) ^ ((lr & 7) << 2))]);
      union { bf16x8 v; unsigned short u[8]; } pa;
      pa.u[0] = f2bf(p0.x); pa.u[1] = f2bf(p0.y); pa.u[2] = f2bf(p0.z); pa.u[3] = f2bf(p0.w);
      pa.u[4] = f2bf(p1.x); pa.u[5] = f2bf(p1.y); pa.u[6] = f2bf(p1.z); pa.u[7] = f2bf(p1.w);
      #pragma unroll
      for (int dt = 0; dt < 8; ++dt){
        bf16x8 vf = *reinterpret_cast<const bf16x8*>(&Vs[dt * 16 + lr][kc * 32 + lg * 8]);
        o[dt] = __builtin_amdgcn_mfma_f32_16x16x32_bf16(pa.v, vf, o[dt], 0, 0, 0);
      }
    }
    __builtin_amdgcn_s_setprio(0);
    __syncthreads();   // Ps(=Ks) + Vs free for next tile
  }

  if (nc == 1){
    // ---- final: O /= l; write AO in (B,T,C) bf16 ----
    float inv[4];
    #pragma unroll
    for (int r = 0; r < 4; ++r) inv[r] = 1.0f / lrun[r];
    #pragma unroll
    for (int dt = 0; dt < 8; ++dt)
      #pragma unroll
      for (int r = 0; r < 4; ++r)
        AO[((size_t)b * T_SEQ + qw + lg * 4 + r) * CDIM + h * HD + dt * 16 + lr] =
            f2bf(o[dt][r] * inv[r]);
  } else {
    // ---- partial: unnormalized O + m,l per row ----
    const int slot = bh * 80 + offq(q) + c;
    float* OpW = Op + (size_t)slot * 64 * 128;
    #pragma unroll
    for (int dt = 0; dt < 8; ++dt)
      #pragma unroll
      for (int r = 0; r < 4; ++r)
        OpW[(wave * 16 + lg * 4 + r) * 128 + dt * 16 + lr] = o[dt][r];
    if (lr == 0){
      #pragma unroll
      for (int r = 0; r < 4; ++r){
        int row = wave * 16 + lg * 4 + r;
        Mp[(size_t)slot * 64 + row] = mrun[r];
        Lp[(size_t)slot * 64 + row] = lrun[r];
      }
    }
  }
}

// ---------------- combine partials for q-blocks with nc>=2 ----------------
__global__ __launch_bounds__(256) void attn_combine(
    const float* __restrict__ Op, const float* __restrict__ Mp,
    const float* __restrict__ Lp, unsigned short* __restrict__ AO)
{
  const int q  = 8 + blockIdx.x;            // 8..31
  const int bh = blockIdx.y;
  const int b = bh / NH, h = bh % NH;
  const int nc = (q + 8) >> 3;
  const int slot0 = bh * 80 + offq(q);
  #pragma unroll
  for (int u = 0; u < 8; ++u){
    int unit = threadIdx.x + u * 256;       // 64 rows x 32 f32x4 cols
    int r = unit >> 5, d4 = unit & 31;
    float m = -__builtin_inff();
    for (int cc = 0; cc < nc; ++cc)
      m = fmaxf(m, Mp[(size_t)(slot0 + cc) * 64 + r]);
    float l = 0.f;
    float a0 = 0.f, a1 = 0.f, a2 = 0.f, a3 = 0.f;
    for (int cc = 0; cc < nc; ++cc){
      float w = __expf(Mp[(size_t)(slot0 + cc) * 64 + r] - m);
      l += w * Lp[(size_t)(slot0 + cc) * 64 + r];
      const float4 v = *reinterpret_cast<const float4*>(
          &Op[((size_t)(slot0 + cc) * 64 + r) * 128 + d4 * 4]);
      a0 += w * v.x; a1 += w * v.y; a2 += w * v.z; a3 += w * v.w;
    }
    float inv = 1.0f / l;
    ushort4 ov;
    ov.x = f2bf(a0 * inv); ov.y = f2bf(a1 * inv);
    ov.z = f2bf(a2 * inv); ov.w = f2bf(a3 * inv);
    *reinterpret_cast<ushort4*>(
        &AO[((size_t)b * T_SEQ + q * 64 + r) * CDIM + h * HD + d4 * 4]) = ov;
  }
}

// ---------------- launch ----------------
extern "C" void kernel_launch(void* const* d_in, const int* in_sizes, int n_in,
                              void* d_out, int out_size, void* d_ws, size_t ws_size,
                              hipStream_t stream)
{
  (void)in_sizes; (void)n_in; (void)out_size;
  const float* x    = (const float*)d_in[0];
  const float* cosp = (const float*)d_in[1];
  const float* sinp = (const float*)d_in[2];
  const float* Wq   = (const float*)d_in[3];
  const float* Wk   = (const float*)d_in[4];
  const float* Wv   = (const float*)d_in[5];
  const float* Wo   = (const float*)d_in[6];
  float* out = (float*)d_out;

  // workspace layout: bf16 region then f32 partials
  unsigned short* xb    = (unsigned short*)d_ws;
  unsigned short* Wqkvb = xb    + (size_t)MROWS * CDIM;
  unsigned short* Wob   = Wqkvb + (size_t)NQKV * CDIM;
  unsigned short* QKVb  = Wob   + (size_t)CDIM * CDIM;
  unsigned short* Vtb   = QKVb  + (size_t)MROWS * NQKV;
  unsigned short* AO    = Vtb   + (size_t)MROWS * CDIM;
  float* Op = (float*)(AO + (size_t)MROWS * CDIM);
  float* Mp = Op + (size_t)NSLOT * 64 * 128;
  float* Lp = Mp + (size_t)NSLOT * 64;
  size_t need = (size_t)((char*)(Lp + (size_t)NSLOT * 64) - (char*)d_ws);
  const int split = (ws_size >= need) ? 1 : 0;

  int n4x = MROWS * CDIM / 4;
  cvt_f32_bf16<<<(n4x + 255) / 256, 256, 0, stream>>>(x, xb, n4x);
  cvt_w4<<<dim3(CDIM * CDIM / 4 / 256, 4), 256, 0, stream>>>(Wq, Wk, Wv, Wo, Wqkvb);

  // fused QKV projection: (8192x768) @ (2304x768)^T -> bf16 QKV
  gemm_bt<1><<<dim3(MROWS / 128, NQKV / 128), 256, 0, stream>>>(xb, Wqkvb, QKVb, MROWS, NQKV, CDIM);
  // RoPE + RMSNorm in place on Q,K slices of QKV
  rope_rms<<<dim3(MROWS, 3), 256, 0, stream>>>(QKVb, cosp, sinp);
  // V transpose -> Vt (B*H, D, T)
  transpose_v<<<dim3(T_SEQ / 64, 12, 4), 256, 0, stream>>>(QKVb, Vtb);
  // causal flash attention, split-KV -> AO (+partials)
  attn_fwd<<<dim3(split ? 80 : 32, 4 * NH), 256, 0, stream>>>(
      QKVb, Vtb, AO, Op, Mp, Lp, split);
  if (split)
    attn_combine<<<dim3(24, 24), 256, 0, stream>>>(Op, Mp, Lp, AO);
  // output projection -> f32 d_out
  gemm_bt<0><<<dim3(MROWS / 128, CDIM / 128), 256, 0, stream>>>(AO, Wob, out, MROWS, CDIM, CDIM);
}